// Round 5
// baseline (122.324 us; speedup 1.0000x reference)
//
#include <hip/hip_runtime.h>
#include <cfloat>

#define SB 1024   // sequence length S = H*W
#define CC 512    // channels
#define NB 8      // batch
#define NH 8      // heads
#define HD 64     // head dim

typedef short short8 __attribute__((ext_vector_type(8)));
typedef short s16x4 __attribute__((ext_vector_type(4)));
typedef float f32x4 __attribute__((ext_vector_type(4)));

__device__ __forceinline__ short f2bs(float f) {
    union { float f; unsigned u; } x; x.f = f;
    unsigned r = x.u + 0x7fffu + ((x.u >> 16) & 1u);   // RNE to bf16
    return (short)(r >> 16);
}

__device__ __forceinline__ float bs2f(short s) {
    union { unsigned u; float f; } x;
    x.u = ((unsigned)(unsigned short)s) << 16;
    return x.f;
}

__device__ __forceinline__ void gload16(const void* g, void* l) {
    __builtin_amdgcn_global_load_lds(
        (const __attribute__((address_space(1))) unsigned int*)g,
        (__attribute__((address_space(3))) unsigned int*)l, 16, 0, 0);
}

// swizzled short-index within a [rows][64-short] LDS tile (128B rows)
__device__ __forceinline__ int sidx(int row, int colb) {
    return row * 64 + ((colb ^ ((row & 7) << 4)) >> 1);
}

// ---------------------------------------------------------------------------
// Convert both weight matrices fp32 -> bf16 (natural [o][c] layout).
// ---------------------------------------------------------------------------
__global__ __launch_bounds__(256)
void cvt_weights(const float* __restrict__ w1, const float* __restrict__ w2,
                 short* __restrict__ o1, short* __restrict__ o2)
{
    const int i4 = blockIdx.x * 256 + threadIdx.x;
    const int N1 = 1536 * 512 / 4;
    if (i4 < N1) {
        float4 v = *(const float4*)&w1[(size_t)i4 * 4];
        s16x4 p; p[0] = f2bs(v.x); p[1] = f2bs(v.y); p[2] = f2bs(v.z); p[3] = f2bs(v.w);
        *(s16x4*)&o1[(size_t)i4 * 4] = p;
    } else {
        const int j = i4 - N1;
        float4 v = *(const float4*)&w2[(size_t)j * 4];
        s16x4 p; p[0] = f2bs(v.x); p[1] = f2bs(v.y); p[2] = f2bs(v.z); p[3] = f2bs(v.w);
        *(s16x4*)&o2[(size_t)j * 4] = p;
    }
}

// ---------------------------------------------------------------------------
// x (B, C, S) fp32  ->  xT (B, S, C) bf16   (64x64 LDS tile transpose)
// ---------------------------------------------------------------------------
__global__ __launch_bounds__(256)
void transpose_x(const float* __restrict__ x, short* __restrict__ xT)
{
    const int bs = blockIdx.x, bc = blockIdx.y, b = blockIdx.z;
    const int tid = threadIdx.x;
    __shared__ short T[64][72];
    {
        const int cl = tid >> 4;
        const int s4 = (tid & 15) * 4;
        #pragma unroll
        for (int r = 0; r < 4; ++r) {
            const int c = cl + 16 * r;
            float4 v = *(const float4*)&x[((size_t)b * CC + bc * 64 + c) * SB + bs * 64 + s4];
            T[s4 + 0][c] = f2bs(v.x); T[s4 + 1][c] = f2bs(v.y);
            T[s4 + 2][c] = f2bs(v.z); T[s4 + 3][c] = f2bs(v.w);
        }
    }
    __syncthreads();
    {
        const int sl = tid >> 2;
        const int c16 = (tid & 3) * 16;
        short8 v0 = *(const short8*)&T[sl][c16];
        short8 v1 = *(const short8*)&T[sl][c16 + 8];
        short* dst = &xT[((size_t)b * SB + bs * 64 + sl) * CC + bc * 64 + c16];
        *(short8*)&dst[0] = v0;
        *(short8*)&dst[8] = v1;
    }
}

// ---------------------------------------------------------------------------
// vmean[b][c] = (1/S) sum_t v[b][c][t]  -- for uniform-softmax (fully masked)
// rows. One wave per (b,c) row; 16 bf16 per lane.
// ---------------------------------------------------------------------------
__global__ __launch_bounds__(256)
void vmean_kernel(const short* __restrict__ vN, float* __restrict__ vmean)
{
    const int row = blockIdx.x * 4 + (threadIdx.x >> 6);  // b*CC + c
    const int lane = threadIdx.x & 63;
    const short* p = vN + (size_t)row * SB + lane * 16;
    short8 a = *(const short8*)&p[0];
    short8 b8 = *(const short8*)&p[8];
    float s = 0.f;
    #pragma unroll
    for (int j = 0; j < 8; ++j) s += bs2f(a[j]) + bs2f(b8[j]);
    #pragma unroll
    for (int o = 1; o < 64; o <<= 1) s += __shfl_xor(s, o, 64);
    if (lane == 0) vmean[row] = s * (1.f / 1024.f);
}

// ---------------------------------------------------------------------------
// bf16 MFMA GEMM: Y[b,o,s] = sum_c A[o,c] * X[b,s,c]^T + bias[o]
// 128x128 tile, BK=64, 4 waves (2x2), 4x4 16x16 frags per wave.
// MODE 0 (qkv): o<512 -> qT[b,h,s,d] *0.125; o<1024 -> kT[b,h,s,d]; else v[b,c,s].
// MODE 1 (proj): fp32 out[b,o,s].
// ---------------------------------------------------------------------------
template<int MODE>
__global__ __launch_bounds__(256)
void gemm_bf16(const short* __restrict__ A, const float* __restrict__ bias,
               const short* __restrict__ BT,
               short* __restrict__ qTo, short* __restrict__ kTo,
               short* __restrict__ vo, float* __restrict__ fo)
{
    const int stile = blockIdx.x * 128;
    const int bo    = blockIdx.y;
    const int b     = blockIdx.z;
    const int tid   = threadIdx.x;
    const int wave = tid >> 6, lane = tid & 63, lg = lane >> 4, ln = lane & 15;
    const int wm = wave >> 1, wn = wave & 1;

    __shared__ short Al[128 * 64];
    __shared__ short Bl[128 * 64];

    f32x4 acc[4][4];
    #pragma unroll
    for (int mt = 0; mt < 4; ++mt)
        #pragma unroll
        for (int nt = 0; nt < 4; ++nt) acc[mt][nt] = (f32x4){0.f, 0.f, 0.f, 0.f};

    const char* Ab = (const char*)(A + (size_t)bo * 128 * 512);
    const char* Bb = (const char*)(BT + ((size_t)b * SB + stile) * 512);

    for (int kc = 0; kc < 512; kc += 64) {
        __syncthreads();
        #pragma unroll
        for (int sw = 0; sw < 4; ++sw) {
            const int lin = tid * 16 + sw * 4096;
            const int row = lin >> 7;
            const int scol = (lin & 127) ^ ((row & 7) << 4);
            gload16(Ab + ((size_t)row * 512 + kc) * 2 + scol,
                    (char*)Al + (wave << 10) + (sw << 12));
            gload16(Bb + ((size_t)row * 512 + kc) * 2 + scol,
                    (char*)Bl + (wave << 10) + (sw << 12));
        }
        __syncthreads();
        #pragma unroll
        for (int kk = 0; kk < 2; ++kk) {
            const int colb = kk * 64 + lg * 16;
            short8 a[4], bb[4];
            #pragma unroll
            for (int mt = 0; mt < 4; ++mt)
                a[mt] = *(const short8*)&Al[sidx(wm * 64 + mt * 16 + ln, colb)];
            #pragma unroll
            for (int nt = 0; nt < 4; ++nt)
                bb[nt] = *(const short8*)&Bl[sidx(wn * 64 + nt * 16 + ln, colb)];
            #pragma unroll
            for (int mt = 0; mt < 4; ++mt)
                #pragma unroll
                for (int nt = 0; nt < 4; ++nt)
                    acc[mt][nt] = __builtin_amdgcn_mfma_f32_16x16x32_bf16(
                        a[mt], bb[nt], acc[mt][nt], 0, 0, 0);
        }
    }

    const int s_base = stile + wn * 64;
    if (MODE == 0) {
        if (bo < 8) {   // q or k -> transposed [b,h,s,d]
            short* dst = (bo < 4) ? qTo : kTo;
            const int h = (bo & 3) * 2 + wm;
            const float sc = (bo < 4) ? 0.125f : 1.0f;
            #pragma unroll
            for (int mt = 0; mt < 4; ++mt) {
                const int d0 = mt * 16 + 4 * lg;
                const int o0 = bo * 128 + wm * 64 + d0;
                const float b0 = bias[o0], b1 = bias[o0 + 1],
                            b2 = bias[o0 + 2], b3 = bias[o0 + 3];
                #pragma unroll
                for (int nt = 0; nt < 4; ++nt) {
                    const int s = s_base + nt * 16 + ln;
                    s16x4 pk;
                    pk[0] = f2bs((acc[mt][nt][0] + b0) * sc);
                    pk[1] = f2bs((acc[mt][nt][1] + b1) * sc);
                    pk[2] = f2bs((acc[mt][nt][2] + b2) * sc);
                    pk[3] = f2bs((acc[mt][nt][3] + b3) * sc);
                    *(s16x4*)&dst[(((size_t)b * NH + h) * SB + s) * HD + d0] = pk;
                }
            }
        } else {        // v -> natural [b,c,s]
            #pragma unroll
            for (int mt = 0; mt < 4; ++mt) {
                const int cv0 = (bo - 8) * 128 + wm * 64 + mt * 16 + 4 * lg;
                #pragma unroll
                for (int r = 0; r < 4; ++r) {
                    const float bv = bias[1024 + cv0 + r];
                    #pragma unroll
                    for (int nt = 0; nt < 4; ++nt) {
                        const int s = s_base + nt * 16 + ln;
                        vo[((size_t)b * CC + cv0 + r) * SB + s] = f2bs(acc[mt][nt][r] + bv);
                    }
                }
            }
        }
    } else {            // proj -> fp32 out [b,o,s]
        #pragma unroll
        for (int mt = 0; mt < 4; ++mt) {
            #pragma unroll
            for (int r = 0; r < 4; ++r) {
                const int o = bo * 128 + wm * 64 + mt * 16 + 4 * lg + r;
                const float bv = bias[o];
                #pragma unroll
                for (int nt = 0; nt < 4; ++nt) {
                    const int s = s_base + nt * 16 + ln;
                    fo[((size_t)b * CC + o) * SB + s] = acc[mt][nt][r] + bv;
                }
            }
        }
    }
}

// ---------------------------------------------------------------------------
// Barrier-free MFMA attention.
//  - K/V fragments loaded DIRECTLY from global (L1/L2-resident tiles; both
//    layouts give contiguous 16B/lane loads) -> no staging, no __syncthreads.
//  - Block = (bh, pair a): processes q-tiles a and 15-a sequentially =
//    exactly 17 tile-units per block (uniform work, no straggler CUs/XCDs).
//    Same-(b,h) blocks share blockIdx.x mod 8 -> same XCD L2 for K/V reuse.
//  - Ps is per-wave LDS (within-wave lgkmcnt ordering suffices).
//  - Fully-masked rows (running max stays exactly -FLT_MAX) get ctx = vmean
//    (reference's uniform softmax over all 1024 keys).
// ---------------------------------------------------------------------------
__global__ __launch_bounds__(256)
void attn_mfma(const short* __restrict__ qT, const short* __restrict__ kT,
               const short* __restrict__ vN, const int* __restrict__ mask,
               const float* __restrict__ vmean, short* __restrict__ ctxT)
{
    const int bh = blockIdx.x;            // 0..63
    const int b  = bh >> 3, h = bh & 7;
    const int pa = blockIdx.y;            // 0..7
    const int tid = threadIdx.x;
    const int wave = tid >> 6;
    const int lane = tid & 63;
    const int lg = lane >> 4;
    const int ln = lane & 15;

    __shared__ short Ps[4][16][72];       // per-wave P tile [s][t]

    const short* kbh = kT + (((size_t)b * NH + h) * SB) * HD;   // [s][d]
    const short* vbh = vN + ((size_t)b * CC + h * HD) * SB;     // [d][t]
    const int*   mb  = mask + (size_t)b * SB;
    const float* vmb = vmean + (size_t)b * CC + h * HD;

    #pragma unroll
    for (int half = 0; half < 2; ++half) {
        const int qb = half ? (15 - pa) : pa;

        const short* qrow = qT + (((size_t)b * NH + h) * SB + qb * 64 + wave * 16 + ln) * HD;
        const short8 qa0 = *(const short8*)&qrow[8 * lg];
        const short8 qa1 = *(const short8*)&qrow[32 + 8 * lg];

        float m_[4], l_[4];
        f32x4 acc[4];
        #pragma unroll
        for (int r = 0; r < 4; ++r) { m_[r] = -FLT_MAX; l_[r] = 0.f; }
        #pragma unroll
        for (int nt = 0; nt < 4; ++nt) acc[nt] = (f32x4){0.f, 0.f, 0.f, 0.f};

        for (int t = 0; t <= qb; ++t) {
            const int tb = t * 64;

            // ---- padding-mask loads (issue early) ----
            float mf[4];
            #pragma unroll
            for (int nt = 0; nt < 4; ++nt)
                mf[nt] = (mb[tb + 16 * nt + ln] != 0) ? -FLT_MAX : 0.f;

            // ---- QK^T: K B-frags straight from global (16B/lane) ----
            f32x4 sc[4];
            #pragma unroll
            for (int nt = 0; nt < 4; ++nt) {
                const short* kr = kbh + (size_t)(tb + 16 * nt + ln) * HD;
                const short8 kb0 = *(const short8*)&kr[8 * lg];
                const short8 kb1 = *(const short8*)&kr[32 + 8 * lg];
                f32x4 z = (f32x4){0.f, 0.f, 0.f, 0.f};
                z = __builtin_amdgcn_mfma_f32_16x16x32_bf16(qa0, kb0, z, 0, 0, 0);
                z = __builtin_amdgcn_mfma_f32_16x16x32_bf16(qa1, kb1, z, 0, 0, 0);
                sc[nt] = z;
            }

            // ---- V B-frags: issue now, consumed after softmax (T14) ----
            short8 vb0[4], vb1[4];
            #pragma unroll
            for (int nt = 0; nt < 4; ++nt) {
                const short* vr = vbh + (size_t)(16 * nt + ln) * SB + tb;
                vb0[nt] = *(const short8*)&vr[8 * lg];
                vb1[nt] = *(const short8*)&vr[32 + 8 * lg];
            }

            // ---- padding mask (float add) + causal on diagonal tile ----
            #pragma unroll
            for (int nt = 0; nt < 4; ++nt)
                #pragma unroll
                for (int r = 0; r < 4; ++r) sc[nt][r] += mf[nt];
            if (t == qb) {
                #pragma unroll
                for (int r = 0; r < 4; ++r) {
                    const int so = wave * 16 + 4 * lg + r;
                    #pragma unroll
                    for (int nt = 0; nt < 4; ++nt)
                        if (16 * nt + ln > so) sc[nt][r] = -FLT_MAX;
                }
            }

            // ---- online softmax ----
            #pragma unroll
            for (int r = 0; r < 4; ++r) {
                float mx = fmaxf(fmaxf(sc[0][r], sc[1][r]), fmaxf(sc[2][r], sc[3][r]));
                #pragma unroll
                for (int o = 1; o < 16; o <<= 1)
                    mx = fmaxf(mx, __shfl_xor(mx, o, 64));
                const float mnew = fmaxf(m_[r], mx);
                const float f = __expf(m_[r] - mnew);   // 0-0 -> 1 (all-masked rows)
                float p[4], rs = 0.f;
                #pragma unroll
                for (int nt = 0; nt < 4; ++nt) {
                    p[nt] = __expf(sc[nt][r] - mnew);
                    rs += p[nt];
                }
                #pragma unroll
                for (int o = 1; o < 16; o <<= 1)
                    rs += __shfl_xor(rs, o, 64);
                l_[r] = l_[r] * f + rs;
                m_[r] = mnew;
                #pragma unroll
                for (int nt = 0; nt < 4; ++nt) acc[nt][r] *= f;
                #pragma unroll
                for (int nt = 0; nt < 4; ++nt)
                    Ps[wave][4 * lg + r][16 * nt + ln] = f2bs(p[nt]);
            }

            // ---- PV (Ps roundtrip is within-wave; lgkmcnt orders it) ----
            const short8 pa0 = *(const short8*)&Ps[wave][ln][8 * lg];
            const short8 pa1 = *(const short8*)&Ps[wave][ln][32 + 8 * lg];
            #pragma unroll
            for (int nt = 0; nt < 4; ++nt) {
                acc[nt] = __builtin_amdgcn_mfma_f32_16x16x32_bf16(pa0, vb0[nt], acc[nt], 0, 0, 0);
                acc[nt] = __builtin_amdgcn_mfma_f32_16x16x32_bf16(pa1, vb1[nt], acc[nt], 0, 0, 0);
            }
        }

        // ---- epilogue: normalize (or vmean for fully-masked rows), store ----
        float rl[4];
        #pragma unroll
        for (int r = 0; r < 4; ++r) rl[r] = 1.f / l_[r];
        #pragma unroll
        for (int nt = 0; nt < 4; ++nt) {
            const int c = h * HD + 16 * nt + ln;
            const float vmv = vmb[16 * nt + ln];
            #pragma unroll
            for (int r = 0; r < 4; ++r) {
                const int s = qb * 64 + wave * 16 + 4 * lg + r;
                const float val = (m_[r] == -FLT_MAX) ? vmv : acc[nt][r] * rl[r];
                ctxT[((size_t)b * SB + s) * CC + c] = f2bs(val);
            }
        }
    }
}

extern "C" void kernel_launch(void* const* d_in, const int* in_sizes, int n_in,
                              void* d_out, int out_size, void* d_ws, size_t ws_size,
                              hipStream_t stream) {
    const float* x      = (const float*)d_in[0];
    const int*   amask  = (const int*)d_in[1];
    const float* qkv_w  = (const float*)d_in[2];
    const float* qkv_b  = (const float*)d_in[3];
    const float* proj_w = (const float*)d_in[4];
    const float* proj_b = (const float*)d_in[5];
    float* out = (float*)d_out;

    short* xT    = (short*)d_ws;                       // (B,S,C)
    short* w1b   = xT  + (size_t)NB * SB * CC;         // (1536,512)
    short* w2b   = w1b + (size_t)1536 * 512;           // (512,512)
    short* qT    = w2b + (size_t)512 * 512;            // (B,H,S,D)
    short* kT    = qT  + (size_t)NB * NH * SB * HD;    // (B,H,S,D)
    short* vN    = kT  + (size_t)NB * NH * SB * HD;    // (B,C,S)
    short* ctxT  = vN  + (size_t)NB * CC * SB;         // (B,S,C)
    float* vmean = (float*)(ctxT + (size_t)NB * SB * CC);  // (B,C)

    cvt_weights<<<1024, 256, 0, stream>>>(qkv_w, proj_w, w1b, w2b);
    transpose_x<<<dim3(SB / 64, CC / 64, NB), 256, 0, stream>>>(x, xT);
    gemm_bf16<0><<<dim3(8, 12, NB), 256, 0, stream>>>(
        w1b, qkv_b, xT, qT, kT, vN, nullptr);
    vmean_kernel<<<NB * CC / 4, 256, 0, stream>>>(vN, vmean);
    attn_mfma<<<dim3(NB * NH, 8, 1), 256, 0, stream>>>(qT, kT, vN, amask, vmean, ctxT);
    gemm_bf16<1><<<dim3(8, 4, NB), 256, 0, stream>>>(
        w2b, proj_b, ctxT, nullptr, nullptr, nullptr, out);
}